// Round 2
// baseline (114.048 us; speedup 1.0000x reference)
//
#include <hip/hip_runtime.h>

// LengthRegulator: out[b,p,:] = x[b, searchsorted_right(cumsum(dur[b]), p), :]
// masked to 0 for p >= mel_len[b]; second output mel_len (written as float).
// Shapes fixed by setup_inputs(): B=32, T=1024, C=384, MAX_LEN=8192.
// NOTE: harness passes ALL integer inputs as int32 (int64 in reference -> const int* here).

#define BB 32
#define TT 1024
#define CC 384
#define MAXLEN 8192
#define OUT0 (BB * MAXLEN * CC)   // 100663296 floats

// ---------------- Kernel 1: per-batch cumsum + mel_len ----------------
// one block per batch, 1024 threads, Hillis-Steele scan in LDS.
__global__ void lr_cumsum(const int* __restrict__ dur,
                          int* __restrict__ cum,
                          float* __restrict__ mel_out) {
    __shared__ int lds[TT];
    const int b = blockIdx.x;
    const int t = threadIdx.x;
    lds[t] = dur[b * TT + t];
    __syncthreads();
    for (int off = 1; off < TT; off <<= 1) {
        int v = (t >= off) ? lds[t - off] : 0;
        __syncthreads();
        lds[t] += v;
        __syncthreads();
    }
    cum[b * TT + t] = lds[t];
    if (t == TT - 1) mel_out[b] = (float)lds[t];
}

// ---------------- Kernel 2: searchsorted(right) per output position ----------------
// idx = first i with cum[i] > p, clamped to T-1; -1 when p >= mel_len (masked).
__global__ void lr_search(const int* __restrict__ cum,
                          int* __restrict__ idx) {
    const int b = blockIdx.y;
    const int p = blockIdx.x * blockDim.x + threadIdx.x;
    const int* c = cum + b * TT;
    const int ml = c[TT - 1];
    int r = -1;
    if (p < ml) {
        int lo = 0, hi = TT;
        while (lo < hi) {
            int mid = (lo + hi) >> 1;
            if (c[mid] <= p) lo = mid + 1; else hi = mid;
        }
        r = (lo < TT - 1) ? lo : (TT - 1);
    }
    idx[b * MAXLEN + p] = r;
}

// ---------------- Kernel 3: gather rows of x into out (float4 vectorized) ----------------
// 96 float4 quads per output row; consecutive threads -> consecutive quads -> coalesced.
__global__ void lr_gather(const float4* __restrict__ x4,
                          const int* __restrict__ idx,
                          float4* __restrict__ out4) {
    const unsigned int QPR = CC / 4;                         // 96 quads per row
    const unsigned int NQ = (unsigned int)BB * MAXLEN * QPR; // 25165824
    const unsigned int stride = gridDim.x * blockDim.x;
    for (unsigned int q = blockIdx.x * blockDim.x + threadIdx.x; q < NQ; q += stride) {
        unsigned int row = q / QPR;                // b*MAXLEN + p
        unsigned int lane = q - row * QPR;
        int i = idx[row];
        float4 v = make_float4(0.f, 0.f, 0.f, 0.f);
        if (i >= 0) {
            unsigned int b = row >> 13;            // MAXLEN = 8192 = 2^13
            v = x4[((size_t)b * TT + (unsigned)i) * QPR + lane];
        }
        out4[q] = v;
    }
}

extern "C" void kernel_launch(void* const* d_in, const int* in_sizes, int n_in,
                              void* d_out, int out_size, void* d_ws, size_t ws_size,
                              hipStream_t stream) {
    const float* x   = (const float*)d_in[0];
    const int*   dur = (const int*)d_in[1];   // int64 in reference -> int32 on device
    float* out = (float*)d_out;

    // workspace layout: cum (B*T int32) | idx (B*MAXLEN int32) -> ~1.13 MB
    int* cum = (int*)d_ws;
    int* idx = cum + BB * TT;

    lr_cumsum<<<BB, TT, 0, stream>>>(dur, cum, out + OUT0);

    dim3 g2(MAXLEN / 256, BB);
    lr_search<<<g2, 256, 0, stream>>>(cum, idx);

    lr_gather<<<4096, 256, 0, stream>>>((const float4*)x, idx, (float4*)out);
}

// Round 3
// 86.110 us; speedup vs baseline: 1.3244x; 1.3244x over previous
//
#include <hip/hip_runtime.h>

// LengthRegulator: out[b,p,:] = x[b, searchsorted_right(cumsum(dur[b]), p), :]
// masked to 0 for p >= mel_len[b]; second output mel_len (written as float).
// B=32, T=1024, C=384, MAX_LEN=8192. Durations arrive as int32.

#define BB 32
#define TT 1024
#define CC 384
#define MAXLEN 8192
#define OUT0 (BB * MAXLEN * CC)   // 100663296 floats

typedef float f32x4 __attribute__((ext_vector_type(4)));

// ---------------- Kernel 1: fused per-batch cumsum + searchsorted ----------------
// one block per batch, 1024 threads. Hillis-Steele scan in LDS, then each
// thread binary-searches 8 output positions directly against the LDS scan.
__global__ void lr_prep(const int* __restrict__ dur,
                        int* __restrict__ idx,
                        float* __restrict__ mel_out) {
    __shared__ int lds[TT];
    const int b = blockIdx.x;
    const int t = threadIdx.x;
    lds[t] = dur[b * TT + t];
    __syncthreads();
    for (int off = 1; off < TT; off <<= 1) {
        int v = (t >= off) ? lds[t - off] : 0;
        __syncthreads();
        lds[t] += v;
        __syncthreads();
    }
    const int ml = lds[TT - 1];
    if (t == TT - 1) mel_out[b] = (float)ml;

    #pragma unroll
    for (int k = 0; k < MAXLEN / TT; ++k) {
        int p = t + k * TT;            // coalesced across threads
        int r = -1;
        if (p < ml) {
            int lo = 0, hi = TT;
            while (lo < hi) {          // lo ends as count of cum[i] <= p
                int mid = (lo + hi) >> 1;
                if (lds[mid] <= p) lo = mid + 1; else hi = mid;
            }
            r = (lo < TT - 1) ? lo : (TT - 1);
        }
        idx[b * MAXLEN + p] = r;
    }
}

// ---------------- Kernel 2: gather rows of x into out ----------------
// 96 float4 quads per row. Two independent coalesced streams (q, q+HALF)
// per iteration for ILP; nontemporal stores keep the 402 MB write stream
// out of L2 so x (50 MB) stays cached.
__global__ void lr_gather(const f32x4* __restrict__ x4,
                          const int* __restrict__ idx,
                          f32x4* __restrict__ out4) {
    const unsigned QPR = CC / 4;                              // 96
    const unsigned HALF = (unsigned)BB * MAXLEN * QPR / 2;    // 12582912
    const unsigned stride = gridDim.x * blockDim.x;
    for (unsigned q = blockIdx.x * blockDim.x + threadIdx.x; q < HALF; q += stride) {
        const unsigned q2 = q + HALF;
        unsigned row1 = q / QPR,  lane1 = q  - row1 * QPR;
        unsigned row2 = q2 / QPR, lane2 = q2 - row2 * QPR;
        int i1 = idx[row1];
        int i2 = idx[row2];
        f32x4 v1 = (f32x4)0.f, v2 = (f32x4)0.f;
        if (i1 >= 0) v1 = x4[((row1 >> 13) * TT + (unsigned)i1) * QPR + lane1];
        if (i2 >= 0) v2 = x4[((row2 >> 13) * TT + (unsigned)i2) * QPR + lane2];
        __builtin_nontemporal_store(v1, &out4[q]);
        __builtin_nontemporal_store(v2, &out4[q2]);
    }
}

extern "C" void kernel_launch(void* const* d_in, const int* in_sizes, int n_in,
                              void* d_out, int out_size, void* d_ws, size_t ws_size,
                              hipStream_t stream) {
    const float* x   = (const float*)d_in[0];
    const int*   dur = (const int*)d_in[1];   // int64 in reference -> int32 on device
    float* out = (float*)d_out;

    int* idx = (int*)d_ws;                    // B*MAXLEN int32 = 1 MB

    lr_prep<<<BB, TT, 0, stream>>>(dur, idx, out + OUT0);
    lr_gather<<<4096, 256, 0, stream>>>((const f32x4*)x, idx, (f32x4*)out);
}